// Round 14
// baseline (289.045 us; speedup 1.0000x reference)
//
#include <hip/hip_runtime.h>
#include <hip/hip_bf16.h>

// ---------------------------------------------------------------------------
// GCN forward on MI355X — round 27.
// R26 post-mortem: feat's 16lanes x 8B -> 8lanes x 16B transform WORKED
// (feat dropped below the 41us visibility cutoff; TA-address-bound theory
// validated). R27: replicate the transform to the two remaining 16-lane
// gathers: h2 (16x4B -> 8x8B uint2 view of hF8, 8 rows/wave, 8 accs) and
// lsm (10x4B -> 5x8B uint2 view of zF8, 8 rows/wave, 8-lane softmax reduce,
// uint4/2xfloat4 stores). Numerically identical, just re-laned. Everything
// else frozen from R26. Predicted: h2 ~40->~30, lsm ~35->~28, total
// 270 -> ~248-256. <5us move => gathers floored -> ROOFLINE evaluation.
// ---------------------------------------------------------------------------

#define HID 64
#define LAB 40
#define RSH 8          // 256 rows per bucket
#define RPB (1 << RSH)
#define KMAX 1024      // max buckets (runtime K = 782)
#define TILE_A 6144    // elements per tile block (1024 threads x 6)
#define EPT 6          // elements per thread in bucketA/histB
#define CAPB 6912      // bucketB LDS stage capacity (mean 6400, +6.4 sigma)

typedef __attribute__((ext_vector_type(8))) short short8;
typedef __attribute__((ext_vector_type(4))) float f32x4;

__device__ __forceinline__ float loadF(const void* p, size_t i, int bf16) {
    if (bf16) return __bfloat162float(((const __hip_bfloat16*)p)[i]);
    return ((const float*)p)[i];
}

__device__ __forceinline__ int loadI(const void* p, size_t i, int i64) {
    if (i64) return (int)(((const long long*)p)[i]);
    return ((const int*)p)[i];
}

// packed bf16x2 helpers
__device__ __forceinline__ float bflo(unsigned v) { return __uint_as_float(v << 16); }
__device__ __forceinline__ float bfhi(unsigned v) { return __uint_as_float(v & 0xFFFF0000u); }
__device__ __forceinline__ unsigned bfr16(float x) {
    unsigned u = __float_as_uint(x);
    return (u + 0x7FFFu + ((u >> 16) & 1u)) >> 16;
}
__device__ __forceinline__ unsigned bfpack(float lo, float hi) {
    return bfr16(lo) | (bfr16(hi) << 16);
}

// fp8 e4m3 HW converts
__device__ __forceinline__ unsigned fp8pack4(float a, float b, float c, float d) {
    int r = __builtin_amdgcn_cvt_pk_fp8_f32(a, b, 0, false);
    r = __builtin_amdgcn_cvt_pk_fp8_f32(c, d, r, true);
    return (unsigned)r;
}

// nontemporal int2 load (keep P streams out of L2)
__device__ __forceinline__ void ntload(const int2* P, int idx, int* c, float* w) {
    long long raw = __builtin_nontemporal_load((const long long*)P + idx);
    *c = (int)(unsigned)(raw & 0xFFFFFFFFll);
    *w = __int_as_float((int)(raw >> 32));
}

// 8 fp8 bytes (uint2) -> short8 of bf16 (fp8->bf16 is exact)
__device__ __forceinline__ short8 cvt8(uint2 u) {
    short8 r;
    r[0] = (short)bfr16(__builtin_amdgcn_cvt_f32_fp8((int)u.x, 0));
    r[1] = (short)bfr16(__builtin_amdgcn_cvt_f32_fp8((int)u.x, 1));
    r[2] = (short)bfr16(__builtin_amdgcn_cvt_f32_fp8((int)u.x, 2));
    r[3] = (short)bfr16(__builtin_amdgcn_cvt_f32_fp8((int)u.x, 3));
    r[4] = (short)bfr16(__builtin_amdgcn_cvt_f32_fp8((int)u.y, 0));
    r[5] = (short)bfr16(__builtin_amdgcn_cvt_f32_fp8((int)u.y, 1));
    r[6] = (short)bfr16(__builtin_amdgcn_cvt_f32_fp8((int)u.y, 2));
    r[7] = (short)bfr16(__builtin_amdgcn_cvt_f32_fp8((int)u.y, 3));
    return r;
}

// Merged prep: per-block dtype probe (redundant, cheap) + convw1 slice;
// block 0 additionally zeroes cntB, stages W2 MFMA frags, publishes flags.
__global__ __launch_bounds__(512)
void prep_kernel(const void* W1, const void* b1p, const void* fidxp,
                 const void* W2, uint2* w1q, uint4* w2f, int* cntB,
                 int* flags, int ne) {
    __shared__ int sf[2];
    const int t = threadIdx.x;
    if (t == 0) {
        const unsigned short* u = (const unsigned short*)b1p;
        int bf16 = 1;
        for (int i = 0; i < 64; i += 2)
            if ((unsigned short)(u[i] & 0x7FFF) >= 0x3E80) { bf16 = 0; break; }
        const int* ip = (const int*)fidxp;
        int i64 = 1;
        for (int i = 1; i < 128; i += 2)
            if (ip[i] != 0) { i64 = 0; break; }
        sf[0] = bf16; sf[1] = i64;
        if (blockIdx.x == 0) {
            flags[0] = bf16; flags[1] = i64; flags[2] = 0; flags[3] = 0;
        }
    }
    __syncthreads();
    const int bf16 = sf[0];
    int i = blockIdx.x * 512 + t;
    if (i < ne) {
        float f0 = loadF(W1, (size_t)4 * i,     bf16);
        float f1 = loadF(W1, (size_t)4 * i + 1, bf16);
        float f2 = loadF(W1, (size_t)4 * i + 2, bf16);
        float f3 = loadF(W1, (size_t)4 * i + 3, bf16);
        w1q[i] = make_uint2(bfpack(f0, f1), bfpack(f2, f3));
    }
    if (blockIdx.x == 0) {
        cntB[t] = 0;
        cntB[t + 512] = 0;
        if (t < 384) {
            int tt   = t >> 7;
            int kh   = (t >> 6) & 1;
            int lane = t & 63;
            int col  = tt * 16 + (lane & 15);
            int kb   = kh * 32 + (lane >> 4) * 8;
            unsigned d[4];
#pragma unroll
            for (int q = 0; q < 8; q += 2) {
                float v0 = (col < LAB) ? loadF(W2, (size_t)(kb + q) * LAB + col, bf16) : 0.f;
                float v1 = (col < LAB) ? loadF(W2, (size_t)(kb + q + 1) * LAB + col, bf16) : 0.f;
                d[q >> 1] = bfpack(v0, v1);
            }
            w2f[(tt * 2 + kh) * 64 + lane] = make_uint4(d[0], d[1], d[2], d[3]);
        }
    }
}

// Bucket histogram, tiled EXACTLY like bucketA (one block per TILE_A run).
__global__ __launch_bounds__(1024)
void histB_kernel(const void* fidx, const void* eidx, int* cntB, int* cntPB,
                  const int* flags, int nnz, int nE, int N, int nblk) {
    __shared__ int lh[KMAX];
    lh[threadIdx.x] = 0;
    __syncthreads();
    const int i64 = flags[1];
    const int nT = nnz + nE;
    const int base = blockIdx.x * TILE_A;
#pragma unroll
    for (int k = 0; k < EPT; k++) {
        int i = base + k * 1024 + threadIdx.x;
        if (i < nT) {
            int grow = (i < nnz) ? loadI(fidx, (size_t)i, i64)
                                 : N + loadI(eidx, (size_t)(i - nnz), i64);
            atomicAdd(&lh[grow >> RSH], 1);
        }
    }
    __syncthreads();
    {
        int c = lh[threadIdx.x];
        cntPB[(size_t)threadIdx.x * nblk + blockIdx.x] = c;
        if (c) atomicAdd(&cntB[threadIdx.x], c);
    }
}

// one block per bucket: LDS re-scan of cntB -> bqstart; scan cntPB -> bases.
__global__ __launch_bounds__(1024)
void scanPB_kernel(int* cntPB, const int* cntB, int* bqstart, int nblk, int K) {
    __shared__ int sb[KMAX];
    __shared__ int se[KMAX];
    __shared__ int s[1024];
    const int b = blockIdx.x;
    const int t = threadIdx.x;
    int c0 = (t < K) ? cntB[t] : 0;
    sb[t] = c0;
    __syncthreads();
    for (int off = 1; off < KMAX; off <<= 1) {
        int v = (t >= off) ? sb[t - off] : 0;
        __syncthreads();
        sb[t] += v;
        __syncthreads();
    }
    se[t] = sb[t] - c0;
    if (t == b) bqstart[b] = se[t];
    __syncthreads();
    const int bqs = se[b];
    int x = (t < nblk) ? cntPB[(size_t)b * nblk + t] : 0;
    s[t] = x;
    __syncthreads();
    for (int off = 1; off < 1024; off <<= 1) {
        int v = (t >= off) ? s[t - off] : 0;
        __syncthreads();
        s[t] += v;
        __syncthreads();
    }
    if (t < nblk) cntPB[(size_t)b * nblk + t] = bqs + s[t] - x;
}

// Pass A: register-held tile -> LDS bucket-sort -> coalesced flush to Q.
__global__ __launch_bounds__(1024)
void bucketA_kernel(const void* fidx, const void* fval,
                    const void* eidx, const void* ew,
                    const int* flags, const int* cntPB, int2* Q,
                    int nnz, int nE, int N, int nblk) {
    __shared__ int2 stage[TILE_A];
    __shared__ int hist[KMAX];
    __shared__ int lofs[KMAX + 1];
    __shared__ int delta[KMAX];
    const int i64 = flags[1], bf16 = flags[0];
    const int nT = nnz + nE;
    const int base = blockIdx.x * TILE_A;
    const int t = threadIdx.x;
    hist[t] = 0;
    __syncthreads();

    int key[EPT]; float val[EPT]; int bk[EPT]; int rk[EPT];
#pragma unroll
    for (int k = 0; k < EPT; k++) {
        int i = base + k * 1024 + t;
        bk[k] = -1; rk[k] = 0; key[k] = 0; val[k] = 0.f;
        if (i < nT) {
            int grow, c; float v;
            if (i < nnz) {
                grow = loadI(fidx, (size_t)i, i64);
                c    = loadI(fidx, (size_t)nnz + i, i64);
                v    = loadF(fval, (size_t)i, bf16);
            } else {
                int j = i - nnz;
                grow = N + loadI(eidx, (size_t)j, i64);
                c    = loadI(eidx, (size_t)nE + j, i64);
                v    = loadF(ew, (size_t)j, bf16);
            }
            int b = grow >> RSH;
            bk[k]  = b;
            key[k] = ((grow & (RPB - 1)) << 17) | c;
            val[k] = v;
            rk[k]  = atomicAdd(&hist[b], 1);
        }
    }
    __syncthreads();

    int cnt = hist[t];
    delta[t] = cnt;
    __syncthreads();
    for (int off2 = 1; off2 < KMAX; off2 <<= 1) {
        int v2 = (t >= off2) ? delta[t - off2] : 0;
        __syncthreads();
        delta[t] += v2;
        __syncthreads();
    }
    {
        int incl = delta[t];
        int excl = incl - cnt;
        lofs[t] = excl;
        if (t == KMAX - 1) lofs[KMAX] = incl;
        delta[t] = cntPB[(size_t)t * nblk + blockIdx.x] - excl;
    }
    __syncthreads();

#pragma unroll
    for (int k = 0; k < EPT; k++) {
        if (bk[k] >= 0)
            stage[lofs[bk[k]] + rk[k]] = make_int2(key[k], __float_as_int(val[k]));
    }
    __syncthreads();

    const int total = min(TILE_A, nT - base);
    for (int p = t; p < total; p += 1024) {
        int b = 0;
#pragma unroll
        for (int step = KMAX / 2; step; step >>= 1)
            if (lofs[b + step] <= p) b += step;
        Q[delta[b] + p] = stage[p];
    }
}

// Pass B: per-bucket row hist/scan -> rp; LDS row-sorted stage -> coalesced P.
__global__ __launch_bounds__(1024)
void bucketB_kernel(const int2* Q, const int* bqstart, int* rp,
                    int2* P, int nT, int K) {
    __shared__ int2 stg[CAPB];
    __shared__ int lh[RPB];
    __shared__ int s[RPB];
    __shared__ int lstart[RPB];
    const int b = blockIdx.x;
    const int t = threadIdx.x;
    const int start = bqstart[b];
    const int end = (b == K - 1) ? nT : bqstart[b + 1];
    const int cnt = end - start;
    if (t < RPB) lh[t] = 0;
    __syncthreads();
    for (int i = start + t; i < end; i += 1024)
        atomicAdd(&lh[((unsigned)Q[i].x) >> 17], 1);
    __syncthreads();
    int x = (t < RPB) ? lh[t] : 0;
    if (t < RPB) s[t] = x;
    __syncthreads();
    for (int off = 1; off < RPB; off <<= 1) {
        int v = (t >= off && t < RPB) ? s[t - off] : 0;
        __syncthreads();
        if (t < RPB) s[t] += v;
        __syncthreads();
    }
    if (t < RPB) {
        int excl = s[t] - x;
        rp[(b << RSH) + t] = start + excl;
        lstart[t] = excl;
        lh[t] = 0;
    }
    __syncthreads();
    if (cnt <= CAPB) {
        for (int i = start + t; i < end; i += 1024) {
            int2 el = Q[i];
            int lr = ((unsigned)el.x) >> 17;
            int rank = atomicAdd(&lh[lr], 1);
            stg[lstart[lr] + rank] = make_int2(el.x & 0x1FFFF, el.y);
        }
        __syncthreads();
        for (int p = t; p < cnt; p += 1024)
            P[start + p] = stg[p];
    } else {
        for (int i = start + t; i < end; i += 1024) {
            int2 el = Q[i];
            int lr = ((unsigned)el.x) >> 17;
            int rank = atomicAdd(&lh[lr], 1);
            P[start + lstart[lr] + rank] = make_int2(el.x & 0x1FFFF, el.y);
        }
    }
}

// 8 rows/wave feat gather: 8 lanes/row, lane owns 8 dims via uint4 view of
// w1q. P prefetch, 8-element chunks. (R26 version, validated)
__global__ void gather_feat_kernel(const int* rp, const int2* P,
                                   const uint2* w1q, const void* b1,
                                   unsigned* hF8, const int* flags, int N) {
    int bf16 = flags[0];
    int wave = (blockIdx.x * blockDim.x + threadIdx.x) >> 6;
    int lane = threadIdx.x & 63;
    int g = lane >> 3, gl = lane & 7;
    int row = 8 * wave + g;
    int s = 0, e = 0;
    if (row < N) { s = rp[row]; e = rp[row + 1]; }
    const uint4* w1q4 = (const uint4*)w1q;
    float a0 = loadF(b1, (size_t)8 * gl,     bf16);
    float a1 = loadF(b1, (size_t)8 * gl + 1, bf16);
    float a2 = loadF(b1, (size_t)8 * gl + 2, bf16);
    float a3 = loadF(b1, (size_t)8 * gl + 3, bf16);
    float a4 = loadF(b1, (size_t)8 * gl + 4, bf16);
    float a5 = loadF(b1, (size_t)8 * gl + 5, bf16);
    float a6 = loadF(b1, (size_t)8 * gl + 6, bf16);
    float a7 = loadF(b1, (size_t)8 * gl + 7, bf16);
    const int sb = g << 3;
    int cl = 0; float vl = 0.f;
    if (s + gl < e) ntload(P, s + gl, &cl, &vl);
    for (int base = s; base < e; base += 8) {
        int ncl = 0; float nvl = 0.f;
        int nidx = base + 8 + gl;
        if (nidx < e) ntload(P, nidx, &ncl, &nvl);
        int cnt = min(8, e - base);
        if (cnt == 8) {
            int   cc[8]; float vv[8];
#pragma unroll
            for (int j = 0; j < 8; j++) {
                cc[j] = __shfl(cl, sb + j);
                vv[j] = __shfl(vl, sb + j);
            }
            uint4 uu[8];
#pragma unroll
            for (int j = 0; j < 8; j++) uu[j] = w1q4[cc[j] * 8 + gl];
#pragma unroll
            for (int j = 0; j < 8; j++) {
                a0 += vv[j] * bflo(uu[j].x); a1 += vv[j] * bfhi(uu[j].x);
                a2 += vv[j] * bflo(uu[j].y); a3 += vv[j] * bfhi(uu[j].y);
                a4 += vv[j] * bflo(uu[j].z); a5 += vv[j] * bfhi(uu[j].z);
                a6 += vv[j] * bflo(uu[j].w); a7 += vv[j] * bfhi(uu[j].w);
            }
        } else {
            for (int j = 0; j < cnt; j++) {
                int   c = __shfl(cl, sb + j);
                float v = __shfl(vl, sb + j);
                uint4 u = w1q4[c * 8 + gl];
                a0 += v * bflo(u.x); a1 += v * bfhi(u.x);
                a2 += v * bflo(u.y); a3 += v * bfhi(u.y);
                a4 += v * bflo(u.z); a5 += v * bfhi(u.z);
                a6 += v * bflo(u.w); a7 += v * bfhi(u.w);
            }
        }
        cl = ncl; vl = nvl;
    }
    if (row < N)
        ((uint2*)hF8)[(size_t)row * 8 + gl] =
            make_uint2(fp8pack4(a0, a1, a2, a3), fp8pack4(a4, a5, a6, a7));
}

// 8 rows/wave h2 propagation: 8 lanes/row, lane owns 8 dims via uint2 view
// of hF8 (halves gather addresses). h2 = relu(A @ h), fp8 in / fp8 out.
__global__ void gather_edge_h2_kernel(const int* rp, const int2* P,
                                      const unsigned* hF8, unsigned* h2F8,
                                      int N) {
    int wave = (blockIdx.x * blockDim.x + threadIdx.x) >> 6;
    int lane = threadIdx.x & 63;
    int g = lane >> 3, gl = lane & 7;
    int row = 8 * wave + g;
    int s = 0, e = 0;
    if (row < N) { s = rp[N + row]; e = rp[N + row + 1]; }
    const uint2* hv = (const uint2*)hF8;
    float a0 = 0.f, a1 = 0.f, a2 = 0.f, a3 = 0.f;
    float a4 = 0.f, a5 = 0.f, a6 = 0.f, a7 = 0.f;
    const int sb = g << 3;
    int cl = 0; float wl = 0.f;
    if (s + gl < e) ntload(P, s + gl, &cl, &wl);
    for (int base = s; base < e; base += 8) {
        int ncl = 0; float nwl = 0.f;
        int nidx = base + 8 + gl;
        if (nidx < e) ntload(P, nidx, &ncl, &nwl);
        int cnt = min(8, e - base);
        if (cnt == 8) {
            int   cc[8]; float ww[8];
#pragma unroll
            for (int j = 0; j < 8; j++) {
                cc[j] = __shfl(cl, sb + j);
                ww[j] = __shfl(wl, sb + j);
            }
            uint2 uu[8];
#pragma unroll
            for (int j = 0; j < 8; j++) uu[j] = hv[cc[j] * 8 + gl];
#pragma unroll
            for (int j = 0; j < 8; j++) {
                a0 += ww[j] * __builtin_amdgcn_cvt_f32_fp8((int)uu[j].x, 0);
                a1 += ww[j] * __builtin_amdgcn_cvt_f32_fp8((int)uu[j].x, 1);
                a2 += ww[j] * __builtin_amdgcn_cvt_f32_fp8((int)uu[j].x, 2);
                a3 += ww[j] * __builtin_amdgcn_cvt_f32_fp8((int)uu[j].x, 3);
                a4 += ww[j] * __builtin_amdgcn_cvt_f32_fp8((int)uu[j].y, 0);
                a5 += ww[j] * __builtin_amdgcn_cvt_f32_fp8((int)uu[j].y, 1);
                a6 += ww[j] * __builtin_amdgcn_cvt_f32_fp8((int)uu[j].y, 2);
                a7 += ww[j] * __builtin_amdgcn_cvt_f32_fp8((int)uu[j].y, 3);
            }
        } else {
            for (int j = 0; j < cnt; j++) {
                int   c = __shfl(cl, sb + j);
                float w = __shfl(wl, sb + j);
                uint2 u = hv[c * 8 + gl];
                a0 += w * __builtin_amdgcn_cvt_f32_fp8((int)u.x, 0);
                a1 += w * __builtin_amdgcn_cvt_f32_fp8((int)u.x, 1);
                a2 += w * __builtin_amdgcn_cvt_f32_fp8((int)u.x, 2);
                a3 += w * __builtin_amdgcn_cvt_f32_fp8((int)u.x, 3);
                a4 += w * __builtin_amdgcn_cvt_f32_fp8((int)u.y, 0);
                a5 += w * __builtin_amdgcn_cvt_f32_fp8((int)u.y, 1);
                a6 += w * __builtin_amdgcn_cvt_f32_fp8((int)u.y, 2);
                a7 += w * __builtin_amdgcn_cvt_f32_fp8((int)u.y, 3);
            }
        }
        cl = ncl; wl = nwl;
    }
    if (row < N)
        ((uint2*)h2F8)[(size_t)row * 8 + gl] =
            make_uint2(fp8pack4(fmaxf(a0, 0.f), fmaxf(a1, 0.f),
                                fmaxf(a2, 0.f), fmaxf(a3, 0.f)),
                       fp8pack4(fmaxf(a4, 0.f), fmaxf(a5, 0.f),
                                fmaxf(a6, 0.f), fmaxf(a7, 0.f)));
}

// Dense via MFMA: z = relu_h2 @ W2 + b2, fp8 out. One wave per 16-row tile.
__global__ void dense_mfma_kernel(const unsigned* h2F8, const uint4* w2f,
                                  const void* b2, unsigned char* zb,
                                  const int* flags, int N) {
    int bf16 = flags[0];
    int wid  = (int)((blockIdx.x * blockDim.x + threadIdx.x) >> 6);
    int lane = threadIdx.x & 63;
    int ntiles = (N + 15) >> 4;
    if (wid >= ntiles) return;
    const int g = lane >> 4;
    const int fr = lane & 15;

    int arow = wid * 16 + fr;
    const uint2* hrow = (const uint2*)(h2F8 + (size_t)arow * 16);
    short8 af0 = cvt8(hrow[g]);
    short8 af1 = cvt8(hrow[4 + g]);

    f32x4 acc[3];
#pragma unroll
    for (int t = 0; t < 3; t++) {
        int col = t * 16 + fr;
        float bias = (col < LAB) ? loadF(b2, (size_t)col, bf16) : 0.f;
        acc[t][0] = bias; acc[t][1] = bias; acc[t][2] = bias; acc[t][3] = bias;
        uint4 b0 = w2f[(t * 2 + 0) * 64 + lane];
        uint4 b1 = w2f[(t * 2 + 1) * 64 + lane];
        acc[t] = __builtin_amdgcn_mfma_f32_16x16x32_bf16(
            af0, *(short8*)&b0, acc[t], 0, 0, 0);
        acc[t] = __builtin_amdgcn_mfma_f32_16x16x32_bf16(
            af1, *(short8*)&b1, acc[t], 0, 0, 0);
    }

#pragma unroll
    for (int t = 0; t < 3; t++) {
        int col = t * 16 + fr;
        if (col < LAB) {
#pragma unroll
            for (int q = 0; q < 4; q++) {
                int orow = wid * 16 + g * 4 + q;
                if (orow < N) {
                    int pk = __builtin_amdgcn_cvt_pk_fp8_f32(acc[t][q], acc[t][q], 0, false);
                    zb[(size_t)orow * LAB + col] = (unsigned char)(pk & 0xFF);
                }
            }
        }
    }
}

// 8 rows/wave lsm: 5 act-lanes/row, lane owns 8 labels via uint2 view of
// zF8 (halves gather addresses). z2 = A@z, fused log_softmax -> out.
__global__ void gather_edge_lsm_kernel(const int* rp, const int2* P,
                                       const unsigned* zF8, void* out,
                                       const int* flags, int N) {
    int bf16 = flags[0];
    int wave = (blockIdx.x * blockDim.x + threadIdx.x) >> 6;
    int lane = threadIdx.x & 63;
    int g = lane >> 3, gl = lane & 7;
    int row = 8 * wave + g;
    int s = 0, e = 0;
    if (row < N) { s = rp[N + row]; e = rp[N + row + 1]; }
    const uint2* zv = (const uint2*)zF8;
    float a0 = 0.f, a1 = 0.f, a2 = 0.f, a3 = 0.f;
    float a4 = 0.f, a5 = 0.f, a6 = 0.f, a7 = 0.f;
    const int sb = g << 3;
    const int act = (gl < 5);
    int cl = 0; float wl = 0.f;
    if (s + gl < e) ntload(P, s + gl, &cl, &wl);
    for (int base = s; base < e; base += 8) {
        int ncl = 0; float nwl = 0.f;
        int nidx = base + 8 + gl;
        if (nidx < e) ntload(P, nidx, &ncl, &nwl);
        int cnt = min(8, e - base);
        if (cnt == 8) {
            int   cc[8]; float ww[8];
#pragma unroll
            for (int j = 0; j < 8; j++) {
                cc[j] = __shfl(cl, sb + j);
                ww[j] = __shfl(wl, sb + j);
            }
            if (act) {
                uint2 uu[8];
#pragma unroll
                for (int j = 0; j < 8; j++) uu[j] = zv[cc[j] * 5 + gl];
#pragma unroll
                for (int j = 0; j < 8; j++) {
                    a0 += ww[j] * __builtin_amdgcn_cvt_f32_fp8((int)uu[j].x, 0);
                    a1 += ww[j] * __builtin_amdgcn_cvt_f32_fp8((int)uu[j].x, 1);
                    a2 += ww[j] * __builtin_amdgcn_cvt_f32_fp8((int)uu[j].x, 2);
                    a3 += ww[j] * __builtin_amdgcn_cvt_f32_fp8((int)uu[j].x, 3);
                    a4 += ww[j] * __builtin_amdgcn_cvt_f32_fp8((int)uu[j].y, 0);
                    a5 += ww[j] * __builtin_amdgcn_cvt_f32_fp8((int)uu[j].y, 1);
                    a6 += ww[j] * __builtin_amdgcn_cvt_f32_fp8((int)uu[j].y, 2);
                    a7 += ww[j] * __builtin_amdgcn_cvt_f32_fp8((int)uu[j].y, 3);
                }
            }
        } else {
            for (int j = 0; j < cnt; j++) {
                int   c = __shfl(cl, sb + j);
                float w = __shfl(wl, sb + j);
                if (act) {
                    uint2 u = zv[c * 5 + gl];
                    a0 += w * __builtin_amdgcn_cvt_f32_fp8((int)u.x, 0);
                    a1 += w * __builtin_amdgcn_cvt_f32_fp8((int)u.x, 1);
                    a2 += w * __builtin_amdgcn_cvt_f32_fp8((int)u.x, 2);
                    a3 += w * __builtin_amdgcn_cvt_f32_fp8((int)u.x, 3);
                    a4 += w * __builtin_amdgcn_cvt_f32_fp8((int)u.y, 0);
                    a5 += w * __builtin_amdgcn_cvt_f32_fp8((int)u.y, 1);
                    a6 += w * __builtin_amdgcn_cvt_f32_fp8((int)u.y, 2);
                    a7 += w * __builtin_amdgcn_cvt_f32_fp8((int)u.y, 3);
                }
            }
        }
        cl = ncl; wl = nwl;
    }
    float m = act ? fmaxf(fmaxf(fmaxf(a0, a1), fmaxf(a2, a3)),
                          fmaxf(fmaxf(a4, a5), fmaxf(a6, a7))) : -INFINITY;
#pragma unroll
    for (int off = 4; off; off >>= 1) m = fmaxf(m, __shfl_xor(m, off));
    float es = act ? (__expf(a0 - m) + __expf(a1 - m) + __expf(a2 - m) + __expf(a3 - m) +
                      __expf(a4 - m) + __expf(a5 - m) + __expf(a6 - m) + __expf(a7 - m)) : 0.f;
#pragma unroll
    for (int off = 4; off; off >>= 1) es += __shfl_xor(es, off);
    float lse = m + __logf(es);
    if (act && row < N) {
        float o0 = a0 - lse, o1 = a1 - lse, o2 = a2 - lse, o3 = a3 - lse;
        float o4 = a4 - lse, o5 = a5 - lse, o6 = a6 - lse, o7 = a7 - lse;
        if (bf16) {
            ((uint4*)out)[(size_t)row * 5 + gl] =
                make_uint4(bfpack(o0, o1), bfpack(o2, o3),
                           bfpack(o4, o5), bfpack(o6, o7));
        } else {
            ((float4*)out)[(size_t)row * 10 + 2 * gl]     = make_float4(o0, o1, o2, o3);
            ((float4*)out)[(size_t)row * 10 + 2 * gl + 1] = make_float4(o4, o5, o6, o7);
        }
    }
}

extern "C" void kernel_launch(void* const* d_in, const int* in_sizes, int n_in,
                              void* d_out, int out_size, void* d_ws, size_t ws_size,
                              hipStream_t stream) {
    const void* fidx = d_in[0];
    const void* fval = d_in[1];
    const void* eidx = d_in[2];
    const void* ew   = d_in[3];
    const void* W1   = d_in[4];
    const void* b1   = d_in[5];
    const void* W2   = d_in[6];
    const void* b2   = d_in[7];

    const int nnz = in_sizes[1];          // 2,500,000
    const int nW1 = in_sizes[4];          // 2048*64
    const int nE  = in_sizes[3];          // 1,700,000
    const int N   = out_size / LAB;       // 100,000
    const int M   = 2 * N;
    const int nT  = nnz + nE;
    const int K   = (M + RPB - 1) >> RSH;          // 782 buckets
    const int NBLK = (nT + TILE_A - 1) / TILE_A;   // 684 tile blocks

    auto align256 = [](size_t x) { return (x + 255) & ~(size_t)255; };
    char* ws = (char*)d_ws;
    size_t off = 0;
    int*   flags   = (int*)(ws + off);   off += 256;
    char*  front   = ws + off;
    unsigned* hF8  = (unsigned*)front;                       // N*16 dwords
    unsigned* h2F8 = hF8 + (size_t)N * 16;                   // N*16 dwords
    unsigned char* zb = (unsigned char*)(h2F8 + (size_t)N * 16);  // N*40 B
    size_t frontBytes = (size_t)N * (64 + 64 + 40);
    size_t qBytes     = (size_t)nT * 8;
    off += align256(frontBytes > qBytes ? frontBytes : qBytes);
    int2*  P       = (int2*)(ws + off);  off += align256((size_t)nT * 8);
    int*   rp      = (int*)(ws + off);   off += align256(((size_t)KMAX << RSH) * 4 + 16);
    uint2* w1q     = (uint2*)(ws + off); off += align256((size_t)nW1 * 2);
    uint4* w2f     = (uint4*)(ws + off); off += align256((size_t)384 * 16);
    int*   cntB    = (int*)(ws + off);   off += KMAX * 4;
    int*   bqstart = (int*)(ws + off);   off += KMAX * 4;
    int*   cntPB   = (int*)(ws + off);   off += align256((size_t)KMAX * NBLK * 4);
    int2*  Q       = (int2*)front;

    // 1. merged prep: flags probe + cntB zero + W1 pack + W2 MFMA frags
    prep_kernel<<<(nW1 / 4 + 511) / 512, 512, 0, stream>>>(
        W1, b1, fidx, W2, w1q, w2f, cntB, flags, nW1 / 4);

    // 2. bucket histogram, tiled like bucketA -> per-(bucket,block) counts
    histB_kernel<<<NBLK, 1024, 0, stream>>>(fidx, eidx, cntB, cntPB,
                                            flags, nnz, nE, N, NBLK);

    // 3. per-bucket scan (incl. own bqstart from cntB re-scan)
    scanPB_kernel<<<K, 1024, 0, stream>>>(cntPB, cntB, bqstart, NBLK, K);

    // 4. pass A: register tile -> LDS bucket-sort -> coalesced scatter into Q
    bucketA_kernel<<<NBLK, 1024, 0, stream>>>(fidx, fval, eidx, ew, flags,
                                              cntPB, Q, nnz, nE, N, NBLK);

    // 5. pass B: per-bucket row sort via LDS staging -> coalesced P + rp
    bucketB_kernel<<<K, 1024, 0, stream>>>(Q, bqstart, rp, P, nT, K);

    // 6. h = sparse_features @ W1 + b1 -> fp8 (8 rows/wave, uint4 gathers)
    int fw = (N + 7) / 8;
    int fblocks = (int)(((size_t)fw * 64 + 255) / 256);
    gather_feat_kernel<<<fblocks, 256, 0, stream>>>(rp, P, w1q, b1, hF8, flags, N);

    // 7. h2 = relu(A @ h) -> fp8 (8 rows/wave, uint2 gathers)
    gather_edge_h2_kernel<<<fblocks, 256, 0, stream>>>(rp, P, hF8, h2F8, N);

    // 8. z = h2 @ W2 + b2 -> fp8 via MFMA (one wave per 16-row tile)
    int ntiles = (N + 15) / 16;
    int dblocks = (int)(((size_t)ntiles * 64 + 255) / 256);
    dense_mfma_kernel<<<dblocks, 256, 0, stream>>>(h2F8, w2f, b2, zb, flags, N);

    // 9. out = log_softmax(A @ z) (8 rows/wave, uint2 gathers)
    gather_edge_lsm_kernel<<<fblocks, 256, 0, stream>>>(rp, P, (const unsigned*)zb,
                                                        d_out, flags, N);
}

// Round 15
// 267.973 us; speedup vs baseline: 1.0786x; 1.0786x over previous
//
#include <hip/hip_runtime.h>
#include <hip/hip_bf16.h>

// ---------------------------------------------------------------------------
// GCN forward on MI355X — round 28 (= exact R26 restore, 270.1us best).
// R27 post-mortem: h2/lsm re-laning REGRESSED (270->289). Line arithmetic:
// feat's w1q row = 128B = 2 lines -> re-lane halved instructions at constant
// lines (win); h2's hF8 row = 64B = ONE line -> 16 lanes x 4B was already
// 1 line/row, re-lane doubled lines/inst (loss). lsm same (40B row + 3/8
// lanes idle). Transform only wins when row spans >=2 cache lines.
// R28: revert h2/lsm to R24 16-lane versions; feat stays 8-lane uint4.
// This is the best-verified configuration. Structural-floor evidence now:
// bucketA parked (~40us x3 structures), gathers TA-bound (both re-lane
// directions explored), ~41us harness fill in timed path.
// ---------------------------------------------------------------------------

#define HID 64
#define LAB 40
#define RSH 8          // 256 rows per bucket
#define RPB (1 << RSH)
#define KMAX 1024      // max buckets (runtime K = 782)
#define TILE_A 6144    // elements per tile block (1024 threads x 6)
#define EPT 6          // elements per thread in bucketA/histB
#define CAPB 6912      // bucketB LDS stage capacity (mean 6400, +6.4 sigma)

typedef __attribute__((ext_vector_type(8))) short short8;
typedef __attribute__((ext_vector_type(4))) float f32x4;

__device__ __forceinline__ float loadF(const void* p, size_t i, int bf16) {
    if (bf16) return __bfloat162float(((const __hip_bfloat16*)p)[i]);
    return ((const float*)p)[i];
}

__device__ __forceinline__ int loadI(const void* p, size_t i, int i64) {
    if (i64) return (int)(((const long long*)p)[i]);
    return ((const int*)p)[i];
}

// packed bf16x2 helpers
__device__ __forceinline__ float bflo(unsigned v) { return __uint_as_float(v << 16); }
__device__ __forceinline__ float bfhi(unsigned v) { return __uint_as_float(v & 0xFFFF0000u); }
__device__ __forceinline__ unsigned bfr16(float x) {
    unsigned u = __float_as_uint(x);
    return (u + 0x7FFFu + ((u >> 16) & 1u)) >> 16;
}
__device__ __forceinline__ unsigned bfpack(float lo, float hi) {
    return bfr16(lo) | (bfr16(hi) << 16);
}

// fp8 e4m3 HW converts
__device__ __forceinline__ unsigned fp8pack4(float a, float b, float c, float d) {
    int r = __builtin_amdgcn_cvt_pk_fp8_f32(a, b, 0, false);
    r = __builtin_amdgcn_cvt_pk_fp8_f32(c, d, r, true);
    return (unsigned)r;
}

// nontemporal int2 load (keep P streams out of L2)
__device__ __forceinline__ void ntload(const int2* P, int idx, int* c, float* w) {
    long long raw = __builtin_nontemporal_load((const long long*)P + idx);
    *c = (int)(unsigned)(raw & 0xFFFFFFFFll);
    *w = __int_as_float((int)(raw >> 32));
}

// 8 fp8 bytes (uint2) -> short8 of bf16 (fp8->bf16 is exact)
__device__ __forceinline__ short8 cvt8(uint2 u) {
    short8 r;
    r[0] = (short)bfr16(__builtin_amdgcn_cvt_f32_fp8((int)u.x, 0));
    r[1] = (short)bfr16(__builtin_amdgcn_cvt_f32_fp8((int)u.x, 1));
    r[2] = (short)bfr16(__builtin_amdgcn_cvt_f32_fp8((int)u.x, 2));
    r[3] = (short)bfr16(__builtin_amdgcn_cvt_f32_fp8((int)u.x, 3));
    r[4] = (short)bfr16(__builtin_amdgcn_cvt_f32_fp8((int)u.y, 0));
    r[5] = (short)bfr16(__builtin_amdgcn_cvt_f32_fp8((int)u.y, 1));
    r[6] = (short)bfr16(__builtin_amdgcn_cvt_f32_fp8((int)u.y, 2));
    r[7] = (short)bfr16(__builtin_amdgcn_cvt_f32_fp8((int)u.y, 3));
    return r;
}

// Merged prep: per-block dtype probe (redundant, cheap) + convw1 slice;
// block 0 additionally zeroes cntB, stages W2 MFMA frags, publishes flags.
__global__ __launch_bounds__(512)
void prep_kernel(const void* W1, const void* b1p, const void* fidxp,
                 const void* W2, uint2* w1q, uint4* w2f, int* cntB,
                 int* flags, int ne) {
    __shared__ int sf[2];
    const int t = threadIdx.x;
    if (t == 0) {
        const unsigned short* u = (const unsigned short*)b1p;
        int bf16 = 1;
        for (int i = 0; i < 64; i += 2)
            if ((unsigned short)(u[i] & 0x7FFF) >= 0x3E80) { bf16 = 0; break; }
        const int* ip = (const int*)fidxp;
        int i64 = 1;
        for (int i = 1; i < 128; i += 2)
            if (ip[i] != 0) { i64 = 0; break; }
        sf[0] = bf16; sf[1] = i64;
        if (blockIdx.x == 0) {
            flags[0] = bf16; flags[1] = i64; flags[2] = 0; flags[3] = 0;
        }
    }
    __syncthreads();
    const int bf16 = sf[0];
    int i = blockIdx.x * 512 + t;
    if (i < ne) {
        float f0 = loadF(W1, (size_t)4 * i,     bf16);
        float f1 = loadF(W1, (size_t)4 * i + 1, bf16);
        float f2 = loadF(W1, (size_t)4 * i + 2, bf16);
        float f3 = loadF(W1, (size_t)4 * i + 3, bf16);
        w1q[i] = make_uint2(bfpack(f0, f1), bfpack(f2, f3));
    }
    if (blockIdx.x == 0) {
        cntB[t] = 0;
        cntB[t + 512] = 0;
        if (t < 384) {
            int tt   = t >> 7;
            int kh   = (t >> 6) & 1;
            int lane = t & 63;
            int col  = tt * 16 + (lane & 15);
            int kb   = kh * 32 + (lane >> 4) * 8;
            unsigned d[4];
#pragma unroll
            for (int q = 0; q < 8; q += 2) {
                float v0 = (col < LAB) ? loadF(W2, (size_t)(kb + q) * LAB + col, bf16) : 0.f;
                float v1 = (col < LAB) ? loadF(W2, (size_t)(kb + q + 1) * LAB + col, bf16) : 0.f;
                d[q >> 1] = bfpack(v0, v1);
            }
            w2f[(tt * 2 + kh) * 64 + lane] = make_uint4(d[0], d[1], d[2], d[3]);
        }
    }
}

// Bucket histogram, tiled EXACTLY like bucketA (one block per TILE_A run).
__global__ __launch_bounds__(1024)
void histB_kernel(const void* fidx, const void* eidx, int* cntB, int* cntPB,
                  const int* flags, int nnz, int nE, int N, int nblk) {
    __shared__ int lh[KMAX];
    lh[threadIdx.x] = 0;
    __syncthreads();
    const int i64 = flags[1];
    const int nT = nnz + nE;
    const int base = blockIdx.x * TILE_A;
#pragma unroll
    for (int k = 0; k < EPT; k++) {
        int i = base + k * 1024 + threadIdx.x;
        if (i < nT) {
            int grow = (i < nnz) ? loadI(fidx, (size_t)i, i64)
                                 : N + loadI(eidx, (size_t)(i - nnz), i64);
            atomicAdd(&lh[grow >> RSH], 1);
        }
    }
    __syncthreads();
    {
        int c = lh[threadIdx.x];
        cntPB[(size_t)threadIdx.x * nblk + blockIdx.x] = c;
        if (c) atomicAdd(&cntB[threadIdx.x], c);
    }
}

// one block per bucket: LDS re-scan of cntB -> bqstart; scan cntPB -> bases.
__global__ __launch_bounds__(1024)
void scanPB_kernel(int* cntPB, const int* cntB, int* bqstart, int nblk, int K) {
    __shared__ int sb[KMAX];
    __shared__ int se[KMAX];
    __shared__ int s[1024];
    const int b = blockIdx.x;
    const int t = threadIdx.x;
    int c0 = (t < K) ? cntB[t] : 0;
    sb[t] = c0;
    __syncthreads();
    for (int off = 1; off < KMAX; off <<= 1) {
        int v = (t >= off) ? sb[t - off] : 0;
        __syncthreads();
        sb[t] += v;
        __syncthreads();
    }
    se[t] = sb[t] - c0;
    if (t == b) bqstart[b] = se[t];
    __syncthreads();
    const int bqs = se[b];
    int x = (t < nblk) ? cntPB[(size_t)b * nblk + t] : 0;
    s[t] = x;
    __syncthreads();
    for (int off = 1; off < 1024; off <<= 1) {
        int v = (t >= off) ? s[t - off] : 0;
        __syncthreads();
        s[t] += v;
        __syncthreads();
    }
    if (t < nblk) cntPB[(size_t)b * nblk + t] = bqs + s[t] - x;
}

// Pass A: register-held tile -> LDS bucket-sort -> coalesced flush to Q.
__global__ __launch_bounds__(1024)
void bucketA_kernel(const void* fidx, const void* fval,
                    const void* eidx, const void* ew,
                    const int* flags, const int* cntPB, int2* Q,
                    int nnz, int nE, int N, int nblk) {
    __shared__ int2 stage[TILE_A];
    __shared__ int hist[KMAX];
    __shared__ int lofs[KMAX + 1];
    __shared__ int delta[KMAX];
    const int i64 = flags[1], bf16 = flags[0];
    const int nT = nnz + nE;
    const int base = blockIdx.x * TILE_A;
    const int t = threadIdx.x;
    hist[t] = 0;
    __syncthreads();

    int key[EPT]; float val[EPT]; int bk[EPT]; int rk[EPT];
#pragma unroll
    for (int k = 0; k < EPT; k++) {
        int i = base + k * 1024 + t;
        bk[k] = -1; rk[k] = 0; key[k] = 0; val[k] = 0.f;
        if (i < nT) {
            int grow, c; float v;
            if (i < nnz) {
                grow = loadI(fidx, (size_t)i, i64);
                c    = loadI(fidx, (size_t)nnz + i, i64);
                v    = loadF(fval, (size_t)i, bf16);
            } else {
                int j = i - nnz;
                grow = N + loadI(eidx, (size_t)j, i64);
                c    = loadI(eidx, (size_t)nE + j, i64);
                v    = loadF(ew, (size_t)j, bf16);
            }
            int b = grow >> RSH;
            bk[k]  = b;
            key[k] = ((grow & (RPB - 1)) << 17) | c;
            val[k] = v;
            rk[k]  = atomicAdd(&hist[b], 1);
        }
    }
    __syncthreads();

    int cnt = hist[t];
    delta[t] = cnt;
    __syncthreads();
    for (int off2 = 1; off2 < KMAX; off2 <<= 1) {
        int v2 = (t >= off2) ? delta[t - off2] : 0;
        __syncthreads();
        delta[t] += v2;
        __syncthreads();
    }
    {
        int incl = delta[t];
        int excl = incl - cnt;
        lofs[t] = excl;
        if (t == KMAX - 1) lofs[KMAX] = incl;
        delta[t] = cntPB[(size_t)t * nblk + blockIdx.x] - excl;
    }
    __syncthreads();

#pragma unroll
    for (int k = 0; k < EPT; k++) {
        if (bk[k] >= 0)
            stage[lofs[bk[k]] + rk[k]] = make_int2(key[k], __float_as_int(val[k]));
    }
    __syncthreads();

    const int total = min(TILE_A, nT - base);
    for (int p = t; p < total; p += 1024) {
        int b = 0;
#pragma unroll
        for (int step = KMAX / 2; step; step >>= 1)
            if (lofs[b + step] <= p) b += step;
        Q[delta[b] + p] = stage[p];
    }
}

// Pass B: per-bucket row hist/scan -> rp; LDS row-sorted stage -> coalesced P.
__global__ __launch_bounds__(1024)
void bucketB_kernel(const int2* Q, const int* bqstart, int* rp,
                    int2* P, int nT, int K) {
    __shared__ int2 stg[CAPB];
    __shared__ int lh[RPB];
    __shared__ int s[RPB];
    __shared__ int lstart[RPB];
    const int b = blockIdx.x;
    const int t = threadIdx.x;
    const int start = bqstart[b];
    const int end = (b == K - 1) ? nT : bqstart[b + 1];
    const int cnt = end - start;
    if (t < RPB) lh[t] = 0;
    __syncthreads();
    for (int i = start + t; i < end; i += 1024)
        atomicAdd(&lh[((unsigned)Q[i].x) >> 17], 1);
    __syncthreads();
    int x = (t < RPB) ? lh[t] : 0;
    if (t < RPB) s[t] = x;
    __syncthreads();
    for (int off = 1; off < RPB; off <<= 1) {
        int v = (t >= off && t < RPB) ? s[t - off] : 0;
        __syncthreads();
        if (t < RPB) s[t] += v;
        __syncthreads();
    }
    if (t < RPB) {
        int excl = s[t] - x;
        rp[(b << RSH) + t] = start + excl;
        lstart[t] = excl;
        lh[t] = 0;
    }
    __syncthreads();
    if (cnt <= CAPB) {
        for (int i = start + t; i < end; i += 1024) {
            int2 el = Q[i];
            int lr = ((unsigned)el.x) >> 17;
            int rank = atomicAdd(&lh[lr], 1);
            stg[lstart[lr] + rank] = make_int2(el.x & 0x1FFFF, el.y);
        }
        __syncthreads();
        for (int p = t; p < cnt; p += 1024)
            P[start + p] = stg[p];
    } else {
        for (int i = start + t; i < end; i += 1024) {
            int2 el = Q[i];
            int lr = ((unsigned)el.x) >> 17;
            int rank = atomicAdd(&lh[lr], 1);
            P[start + lstart[lr] + rank] = make_int2(el.x & 0x1FFFF, el.y);
        }
    }
}

// 8 rows/wave feat gather: 8 lanes/row, lane owns 8 dims via uint4 view of
// w1q (w1q row = 128B = 2 lines, re-lane wins). P prefetch, 8-el chunks.
__global__ void gather_feat_kernel(const int* rp, const int2* P,
                                   const uint2* w1q, const void* b1,
                                   unsigned* hF8, const int* flags, int N) {
    int bf16 = flags[0];
    int wave = (blockIdx.x * blockDim.x + threadIdx.x) >> 6;
    int lane = threadIdx.x & 63;
    int g = lane >> 3, gl = lane & 7;
    int row = 8 * wave + g;
    int s = 0, e = 0;
    if (row < N) { s = rp[row]; e = rp[row + 1]; }
    const uint4* w1q4 = (const uint4*)w1q;
    float a0 = loadF(b1, (size_t)8 * gl,     bf16);
    float a1 = loadF(b1, (size_t)8 * gl + 1, bf16);
    float a2 = loadF(b1, (size_t)8 * gl + 2, bf16);
    float a3 = loadF(b1, (size_t)8 * gl + 3, bf16);
    float a4 = loadF(b1, (size_t)8 * gl + 4, bf16);
    float a5 = loadF(b1, (size_t)8 * gl + 5, bf16);
    float a6 = loadF(b1, (size_t)8 * gl + 6, bf16);
    float a7 = loadF(b1, (size_t)8 * gl + 7, bf16);
    const int sb = g << 3;
    int cl = 0; float vl = 0.f;
    if (s + gl < e) ntload(P, s + gl, &cl, &vl);
    for (int base = s; base < e; base += 8) {
        int ncl = 0; float nvl = 0.f;
        int nidx = base + 8 + gl;
        if (nidx < e) ntload(P, nidx, &ncl, &nvl);
        int cnt = min(8, e - base);
        if (cnt == 8) {
            int   cc[8]; float vv[8];
#pragma unroll
            for (int j = 0; j < 8; j++) {
                cc[j] = __shfl(cl, sb + j);
                vv[j] = __shfl(vl, sb + j);
            }
            uint4 uu[8];
#pragma unroll
            for (int j = 0; j < 8; j++) uu[j] = w1q4[cc[j] * 8 + gl];
#pragma unroll
            for (int j = 0; j < 8; j++) {
                a0 += vv[j] * bflo(uu[j].x); a1 += vv[j] * bfhi(uu[j].x);
                a2 += vv[j] * bflo(uu[j].y); a3 += vv[j] * bfhi(uu[j].y);
                a4 += vv[j] * bflo(uu[j].z); a5 += vv[j] * bfhi(uu[j].z);
                a6 += vv[j] * bflo(uu[j].w); a7 += vv[j] * bfhi(uu[j].w);
            }
        } else {
            for (int j = 0; j < cnt; j++) {
                int   c = __shfl(cl, sb + j);
                float v = __shfl(vl, sb + j);
                uint4 u = w1q4[c * 8 + gl];
                a0 += v * bflo(u.x); a1 += v * bfhi(u.x);
                a2 += v * bflo(u.y); a3 += v * bfhi(u.y);
                a4 += v * bflo(u.z); a5 += v * bfhi(u.z);
                a6 += v * bflo(u.w); a7 += v * bfhi(u.w);
            }
        }
        cl = ncl; vl = nvl;
    }
    if (row < N)
        ((uint2*)hF8)[(size_t)row * 8 + gl] =
            make_uint2(fp8pack4(a0, a1, a2, a3), fp8pack4(a4, a5, a6, a7));
}

// Merged propagation with NEXT-CHUNK P PREFETCH: h2 = relu(A @ h), fp8->fp8.
// 16 lanes/row x 4B: hF8 row = 64B = ONE line -> this laning is optimal.
__global__ void gather_edge_h2_kernel(const int* rp, const int2* P,
                                      const unsigned* hF8, unsigned* h2F8,
                                      int N) {
    int wave = (blockIdx.x * blockDim.x + threadIdx.x) >> 6;
    int lane = threadIdx.x & 63;
    int g = lane >> 4, gl = lane & 15;
    int row = 4 * wave + g;
    int s = 0, e = 0;
    if (row < N) { s = rp[N + row]; e = rp[N + row + 1]; }
    float a0 = 0.f, a1 = 0.f, a2 = 0.f, a3 = 0.f;
    const int sb = g << 4;
    int cl = 0; float wl = 0.f;
    if (s + gl < e) ntload(P, s + gl, &cl, &wl);
    for (int base = s; base < e; base += 16) {
        int ncl = 0; float nwl = 0.f;
        int nidx = base + 16 + gl;
        if (nidx < e) ntload(P, nidx, &ncl, &nwl);
        int cnt = min(16, e - base);
        int j = 0;
        for (; j + 8 <= cnt; j += 8) {
            int   c0 = __shfl(cl, sb + j),     c1 = __shfl(cl, sb + j + 1);
            int   c2 = __shfl(cl, sb + j + 2), c3 = __shfl(cl, sb + j + 3);
            int   c4 = __shfl(cl, sb + j + 4), c5 = __shfl(cl, sb + j + 5);
            int   c6 = __shfl(cl, sb + j + 6), c7 = __shfl(cl, sb + j + 7);
            float w0 = __shfl(wl, sb + j),     w1 = __shfl(wl, sb + j + 1);
            float w2 = __shfl(wl, sb + j + 2), w3 = __shfl(wl, sb + j + 3);
            float w4 = __shfl(wl, sb + j + 4), w5 = __shfl(wl, sb + j + 5);
            float w6 = __shfl(wl, sb + j + 6), w7 = __shfl(wl, sb + j + 7);
            int u0 = (int)hF8[c0 * 16 + gl];
            int u1 = (int)hF8[c1 * 16 + gl];
            int u2 = (int)hF8[c2 * 16 + gl];
            int u3 = (int)hF8[c3 * 16 + gl];
            int u4 = (int)hF8[c4 * 16 + gl];
            int u5 = (int)hF8[c5 * 16 + gl];
            int u6 = (int)hF8[c6 * 16 + gl];
            int u7 = (int)hF8[c7 * 16 + gl];
            a0 += w0 * __builtin_amdgcn_cvt_f32_fp8(u0, 0);
            a1 += w0 * __builtin_amdgcn_cvt_f32_fp8(u0, 1);
            a2 += w0 * __builtin_amdgcn_cvt_f32_fp8(u0, 2);
            a3 += w0 * __builtin_amdgcn_cvt_f32_fp8(u0, 3);
            a0 += w1 * __builtin_amdgcn_cvt_f32_fp8(u1, 0);
            a1 += w1 * __builtin_amdgcn_cvt_f32_fp8(u1, 1);
            a2 += w1 * __builtin_amdgcn_cvt_f32_fp8(u1, 2);
            a3 += w1 * __builtin_amdgcn_cvt_f32_fp8(u1, 3);
            a0 += w2 * __builtin_amdgcn_cvt_f32_fp8(u2, 0);
            a1 += w2 * __builtin_amdgcn_cvt_f32_fp8(u2, 1);
            a2 += w2 * __builtin_amdgcn_cvt_f32_fp8(u2, 2);
            a3 += w2 * __builtin_amdgcn_cvt_f32_fp8(u2, 3);
            a0 += w3 * __builtin_amdgcn_cvt_f32_fp8(u3, 0);
            a1 += w3 * __builtin_amdgcn_cvt_f32_fp8(u3, 1);
            a2 += w3 * __builtin_amdgcn_cvt_f32_fp8(u3, 2);
            a3 += w3 * __builtin_amdgcn_cvt_f32_fp8(u3, 3);
            a0 += w4 * __builtin_amdgcn_cvt_f32_fp8(u4, 0);
            a1 += w4 * __builtin_amdgcn_cvt_f32_fp8(u4, 1);
            a2 += w4 * __builtin_amdgcn_cvt_f32_fp8(u4, 2);
            a3 += w4 * __builtin_amdgcn_cvt_f32_fp8(u4, 3);
            a0 += w5 * __builtin_amdgcn_cvt_f32_fp8(u5, 0);
            a1 += w5 * __builtin_amdgcn_cvt_f32_fp8(u5, 1);
            a2 += w5 * __builtin_amdgcn_cvt_f32_fp8(u5, 2);
            a3 += w5 * __builtin_amdgcn_cvt_f32_fp8(u5, 3);
            a0 += w6 * __builtin_amdgcn_cvt_f32_fp8(u6, 0);
            a1 += w6 * __builtin_amdgcn_cvt_f32_fp8(u6, 1);
            a2 += w6 * __builtin_amdgcn_cvt_f32_fp8(u6, 2);
            a3 += w6 * __builtin_amdgcn_cvt_f32_fp8(u6, 3);
            a0 += w7 * __builtin_amdgcn_cvt_f32_fp8(u7, 0);
            a1 += w7 * __builtin_amdgcn_cvt_f32_fp8(u7, 1);
            a2 += w7 * __builtin_amdgcn_cvt_f32_fp8(u7, 2);
            a3 += w7 * __builtin_amdgcn_cvt_f32_fp8(u7, 3);
        }
        for (; j < cnt; j++) {
            int   c = __shfl(cl, sb + j);
            float w = __shfl(wl, sb + j);
            int u = (int)hF8[c * 16 + gl];
            a0 += w * __builtin_amdgcn_cvt_f32_fp8(u, 0);
            a1 += w * __builtin_amdgcn_cvt_f32_fp8(u, 1);
            a2 += w * __builtin_amdgcn_cvt_f32_fp8(u, 2);
            a3 += w * __builtin_amdgcn_cvt_f32_fp8(u, 3);
        }
        cl = ncl; wl = nwl;
    }
    if (row < N)
        h2F8[row * 16 + gl] = fp8pack4(fmaxf(a0, 0.f), fmaxf(a1, 0.f),
                                       fmaxf(a2, 0.f), fmaxf(a3, 0.f));
}

// Dense via MFMA: z = relu_h2 @ W2 + b2, fp8 out. One wave per 16-row tile.
__global__ void dense_mfma_kernel(const unsigned* h2F8, const uint4* w2f,
                                  const void* b2, unsigned char* zb,
                                  const int* flags, int N) {
    int bf16 = flags[0];
    int wid  = (int)((blockIdx.x * blockDim.x + threadIdx.x) >> 6);
    int lane = threadIdx.x & 63;
    int ntiles = (N + 15) >> 4;
    if (wid >= ntiles) return;
    const int g = lane >> 4;
    const int fr = lane & 15;

    int arow = wid * 16 + fr;
    const uint2* hrow = (const uint2*)(h2F8 + (size_t)arow * 16);
    short8 af0 = cvt8(hrow[g]);
    short8 af1 = cvt8(hrow[4 + g]);

    f32x4 acc[3];
#pragma unroll
    for (int t = 0; t < 3; t++) {
        int col = t * 16 + fr;
        float bias = (col < LAB) ? loadF(b2, (size_t)col, bf16) : 0.f;
        acc[t][0] = bias; acc[t][1] = bias; acc[t][2] = bias; acc[t][3] = bias;
        uint4 b0 = w2f[(t * 2 + 0) * 64 + lane];
        uint4 b1 = w2f[(t * 2 + 1) * 64 + lane];
        acc[t] = __builtin_amdgcn_mfma_f32_16x16x32_bf16(
            af0, *(short8*)&b0, acc[t], 0, 0, 0);
        acc[t] = __builtin_amdgcn_mfma_f32_16x16x32_bf16(
            af1, *(short8*)&b1, acc[t], 0, 0, 0);
    }

#pragma unroll
    for (int t = 0; t < 3; t++) {
        int col = t * 16 + fr;
        if (col < LAB) {
#pragma unroll
            for (int q = 0; q < 4; q++) {
                int orow = wid * 16 + g * 4 + q;
                if (orow < N) {
                    int pk = __builtin_amdgcn_cvt_pk_fp8_f32(acc[t][q], acc[t][q], 0, false);
                    zb[(size_t)orow * LAB + col] = (unsigned char)(pk & 0xFF);
                }
            }
        }
    }
}

// 4 rows/wave with NEXT-CHUNK P PREFETCH: z2 = A@z, fused log_softmax -> out.
// 10 act-lanes x 4B: zF8 row = 40B < 1 line -> this laning is optimal.
__global__ void gather_edge_lsm_kernel(const int* rp, const int2* P,
                                       const unsigned* zF8, void* out,
                                       const int* flags, int N) {
    int bf16 = flags[0];
    int wave = (blockIdx.x * blockDim.x + threadIdx.x) >> 6;
    int lane = threadIdx.x & 63;
    int g = lane >> 4, gl = lane & 15;
    int row = 4 * wave + g;
    int s = 0, e = 0;
    if (row < N) { s = rp[N + row]; e = rp[N + row + 1]; }
    float a0 = 0.f, a1 = 0.f, a2 = 0.f, a3 = 0.f;
    const int sb = g << 4;
    const int act = (gl < 10);
    int cl = 0; float wl = 0.f;
    if (s + gl < e) ntload(P, s + gl, &cl, &wl);
    for (int base = s; base < e; base += 16) {
        int ncl = 0; float nwl = 0.f;
        int nidx = base + 16 + gl;
        if (nidx < e) ntload(P, nidx, &ncl, &nwl);
        int cnt = min(16, e - base);
        int j = 0;
        for (; j + 4 <= cnt; j += 4) {
            int   c0 = __shfl(cl, sb + j),     c1 = __shfl(cl, sb + j + 1);
            int   c2 = __shfl(cl, sb + j + 2), c3 = __shfl(cl, sb + j + 3);
            float w0 = __shfl(wl, sb + j),     w1 = __shfl(wl, sb + j + 1);
            float w2 = __shfl(wl, sb + j + 2), w3 = __shfl(wl, sb + j + 3);
            if (act) {
                int u0 = (int)zF8[c0 * 10 + gl];
                int u1 = (int)zF8[c1 * 10 + gl];
                int u2 = (int)zF8[c2 * 10 + gl];
                int u3 = (int)zF8[c3 * 10 + gl];
                a0 += w0 * __builtin_amdgcn_cvt_f32_fp8(u0, 0);
                a1 += w0 * __builtin_amdgcn_cvt_f32_fp8(u0, 1);
                a2 += w0 * __builtin_amdgcn_cvt_f32_fp8(u0, 2);
                a3 += w0 * __builtin_amdgcn_cvt_f32_fp8(u0, 3);
                a0 += w1 * __builtin_amdgcn_cvt_f32_fp8(u1, 0);
                a1 += w1 * __builtin_amdgcn_cvt_f32_fp8(u1, 1);
                a2 += w1 * __builtin_amdgcn_cvt_f32_fp8(u1, 2);
                a3 += w1 * __builtin_amdgcn_cvt_f32_fp8(u1, 3);
                a0 += w2 * __builtin_amdgcn_cvt_f32_fp8(u2, 0);
                a1 += w2 * __builtin_amdgcn_cvt_f32_fp8(u2, 1);
                a2 += w2 * __builtin_amdgcn_cvt_f32_fp8(u2, 2);
                a3 += w2 * __builtin_amdgcn_cvt_f32_fp8(u2, 3);
                a0 += w3 * __builtin_amdgcn_cvt_f32_fp8(u3, 0);
                a1 += w3 * __builtin_amdgcn_cvt_f32_fp8(u3, 1);
                a2 += w3 * __builtin_amdgcn_cvt_f32_fp8(u3, 2);
                a3 += w3 * __builtin_amdgcn_cvt_f32_fp8(u3, 3);
            }
        }
        for (; j < cnt; j++) {
            int   c = __shfl(cl, sb + j);
            float w = __shfl(wl, sb + j);
            if (act) {
                int u = (int)zF8[c * 10 + gl];
                a0 += w * __builtin_amdgcn_cvt_f32_fp8(u, 0);
                a1 += w * __builtin_amdgcn_cvt_f32_fp8(u, 1);
                a2 += w * __builtin_amdgcn_cvt_f32_fp8(u, 2);
                a3 += w * __builtin_amdgcn_cvt_f32_fp8(u, 3);
            }
        }
        cl = ncl; wl = nwl;
    }
    float m = act ? fmaxf(fmaxf(a0, a1), fmaxf(a2, a3)) : -INFINITY;
#pragma unroll
    for (int off = 8; off; off >>= 1) m = fmaxf(m, __shfl_xor(m, off));
    float es = act ? (__expf(a0 - m) + __expf(a1 - m) + __expf(a2 - m) + __expf(a3 - m)) : 0.f;
#pragma unroll
    for (int off = 8; off; off >>= 1) es += __shfl_xor(es, off);
    float lse = m + __logf(es);
    if (act && row < N) {
        float o0 = a0 - lse, o1 = a1 - lse, o2 = a2 - lse, o3 = a3 - lse;
        if (bf16) {
            ((uint2*)out)[(size_t)row * 10 + gl] =
                make_uint2(bfpack(o0, o1), bfpack(o2, o3));
        } else {
            float4 v = make_float4(o0, o1, o2, o3);
            ((float4*)out)[(size_t)row * 10 + gl] = v;
        }
    }
}

extern "C" void kernel_launch(void* const* d_in, const int* in_sizes, int n_in,
                              void* d_out, int out_size, void* d_ws, size_t ws_size,
                              hipStream_t stream) {
    const void* fidx = d_in[0];
    const void* fval = d_in[1];
    const void* eidx = d_in[2];
    const void* ew   = d_in[3];
    const void* W1   = d_in[4];
    const void* b1   = d_in[5];
    const void* W2   = d_in[6];
    const void* b2   = d_in[7];

    const int nnz = in_sizes[1];          // 2,500,000
    const int nW1 = in_sizes[4];          // 2048*64
    const int nE  = in_sizes[3];          // 1,700,000
    const int N   = out_size / LAB;       // 100,000
    const int M   = 2 * N;
    const int nT  = nnz + nE;
    const int K   = (M + RPB - 1) >> RSH;          // 782 buckets
    const int NBLK = (nT + TILE_A - 1) / TILE_A;   // 684 tile blocks

    auto align256 = [](size_t x) { return (x + 255) & ~(size_t)255; };
    char* ws = (char*)d_ws;
    size_t off = 0;
    int*   flags   = (int*)(ws + off);   off += 256;
    char*  front   = ws + off;
    unsigned* hF8  = (unsigned*)front;                       // N*16 dwords
    unsigned* h2F8 = hF8 + (size_t)N * 16;                   // N*16 dwords
    unsigned char* zb = (unsigned char*)(h2F8 + (size_t)N * 16);  // N*40 B
    size_t frontBytes = (size_t)N * (64 + 64 + 40);
    size_t qBytes     = (size_t)nT * 8;
    off += align256(frontBytes > qBytes ? frontBytes : qBytes);
    int2*  P       = (int2*)(ws + off);  off += align256((size_t)nT * 8);
    int*   rp      = (int*)(ws + off);   off += align256(((size_t)KMAX << RSH) * 4 + 16);
    uint2* w1q     = (uint2*)(ws + off); off += align256((size_t)nW1 * 2);
    uint4* w2f     = (uint4*)(ws + off); off += align256((size_t)384 * 16);
    int*   cntB    = (int*)(ws + off);   off += KMAX * 4;
    int*   bqstart = (int*)(ws + off);   off += KMAX * 4;
    int*   cntPB   = (int*)(ws + off);   off += align256((size_t)KMAX * NBLK * 4);
    int2*  Q       = (int2*)front;

    // 1. merged prep: flags probe + cntB zero + W1 pack + W2 MFMA frags
    prep_kernel<<<(nW1 / 4 + 511) / 512, 512, 0, stream>>>(
        W1, b1, fidx, W2, w1q, w2f, cntB, flags, nW1 / 4);

    // 2. bucket histogram, tiled like bucketA -> per-(bucket,block) counts
    histB_kernel<<<NBLK, 1024, 0, stream>>>(fidx, eidx, cntB, cntPB,
                                            flags, nnz, nE, N, NBLK);

    // 3. per-bucket scan (incl. own bqstart from cntB re-scan)
    scanPB_kernel<<<K, 1024, 0, stream>>>(cntPB, cntB, bqstart, NBLK, K);

    // 4. pass A: register tile -> LDS bucket-sort -> coalesced scatter into Q
    bucketA_kernel<<<NBLK, 1024, 0, stream>>>(fidx, fval, eidx, ew, flags,
                                              cntPB, Q, nnz, nE, N, NBLK);

    // 5. pass B: per-bucket row sort via LDS staging -> coalesced P + rp
    bucketB_kernel<<<K, 1024, 0, stream>>>(Q, bqstart, rp, P, nT, K);

    // 6. h = sparse_features @ W1 + b1 -> fp8 (8 rows/wave, uint4 gathers)
    int fw = (N + 7) / 8;
    int fblocks = (int)(((size_t)fw * 64 + 255) / 256);
    gather_feat_kernel<<<fblocks, 256, 0, stream>>>(rp, P, w1q, b1, hF8, flags, N);

    // 7. h2 = relu(A @ h) -> fp8 (16 lanes/row, 1 line/row — optimal)
    int nwaves = (N + 3) / 4;
    int gblocks = (int)(((size_t)nwaves * 64 + 255) / 256);
    gather_edge_h2_kernel<<<gblocks, 256, 0, stream>>>(rp, P, hF8, h2F8, N);

    // 8. z = h2 @ W2 + b2 -> fp8 via MFMA (one wave per 16-row tile)
    int ntiles = (N + 15) / 16;
    int dblocks = (int)(((size_t)ntiles * 64 + 255) / 256);
    dense_mfma_kernel<<<dblocks, 256, 0, stream>>>(h2F8, w2f, b2, zb, flags, N);

    // 9. out = log_softmax(A @ z) (16 lanes/row, 10 active)
    gather_edge_lsm_kernel<<<gblocks, 256, 0, stream>>>(rp, P, (const unsigned*)zb,
                                                        d_out, flags, N);
}